// Round 5
// baseline (342.895 us; speedup 1.0000x reference)
//
#include <hip/hip_runtime.h>
#include <math.h>

// Problem constants (B,S,D fixed by the reference harness)
#define BB 32
#define SS 2048
#define DD 1024
#define EPSF 1e-7f

typedef float vfloat4 __attribute__((ext_vector_type(4)));

// ---------------------------------------------------------------------------
// Kernel 1: proj[b,e] = sum_d y[b,d] * M[e,d]
// Grid 512 blocks x 256 threads. Block = (4 e-rows) x (16 batches).
// 16 y-rows (64 KB) staged in LDS -> M read ~2x total (8 MB HBM).
// b-loop fully unrolled: 16 independent reduce chains interleaved.
// ---------------------------------------------------------------------------
__global__ __launch_bounds__(256) void proj_kernel(const float* __restrict__ y,
                                                   const float* __restrict__ M,
                                                   float* __restrict__ proj) {
    __shared__ vfloat4 yl[16 * 256];         // 16 batches x 1024 floats = 64 KB
    const int eg  = blockIdx.x >> 1;         // 0..255 -> e-group of 4 rows
    const int bh  = blockIdx.x & 1;          // batch half: b in [16*bh, 16*bh+16)
    const int tid = threadIdx.x;

    const vfloat4* __restrict__ ysrc = (const vfloat4*)(y + (size_t)bh * 16 * DD);
#pragma unroll
    for (int k = 0; k < 16; ++k)
        yl[tid + 256 * k] = ysrc[tid + 256 * k];
    __syncthreads();

    const int wave = tid >> 6;
    const int lane = tid & 63;
    const int e = eg * 4 + wave;             // 0..1023

    const vfloat4* __restrict__ Mrow = (const vfloat4*)(M + (size_t)e * DD);
    vfloat4 m[4];
#pragma unroll
    for (int k = 0; k < 4; ++k)
        m[k] = Mrow[lane + 64 * k];          // lane holds 16 floats of M[e,:]

    float acc[16];
#pragma unroll
    for (int b = 0; b < 16; ++b) {
        float a = 0.f;
#pragma unroll
        for (int k = 0; k < 4; ++k) {
            const vfloat4 yv = yl[b * 256 + lane + 64 * k];  // conflict-free b128
            a += m[k].x * yv.x + m[k].y * yv.y + m[k].z * yv.z + m[k].w * yv.w;
        }
        acc[b] = a;
    }
#pragma unroll
    for (int off = 32; off >= 1; off >>= 1) {
#pragma unroll
        for (int b = 0; b < 16; ++b)
            acc[b] += __shfl_xor(acc[b], off, 64);
    }
    if (lane == 0) {
#pragma unroll
        for (int b = 0; b < 16; ++b)
            proj[(size_t)(bh * 16 + b) * DD + e] = acc[b];
    }
}

// ---------------------------------------------------------------------------
// Kernel 2: t[b,s] = mask ? exp(tanh(sum_d x[b,s,d]*proj[b,d])) : 0
// One wave per FOUR consecutive rows. R5 change: PLAIN x loads (nontemporal
// removed — single-variable test of whether the nt flag throttles streaming
// read BW on gfx950). Everything else identical to R4.
// ---------------------------------------------------------------------------
__global__ __launch_bounds__(256) void score_kernel(const float* __restrict__ x,
                                                    const int* __restrict__ mask,
                                                    const float* __restrict__ proj,
                                                    float* __restrict__ t) {
    const int wave = (blockIdx.x * 256 + threadIdx.x) >> 6;   // 0..16383
    const int lane = threadIdx.x & 63;
    const int b  = wave >> 9;                // 512 waves per batch
    const int s0 = (wave & 511) << 2;        // row index, multiple of 4
    const size_t base = (size_t)b * SS + s0;

    const int4 mm = *(const int4*)(mask + base);   // 16B-aligned broadcast
    const int msk[4] = {mm.x, mm.y, mm.z, mm.w};
    if ((mm.x | mm.y | mm.z | mm.w) == 0) {
        if (lane == 0) {
            vfloat4 z; z.x = 0.f; z.y = 0.f; z.z = 0.f; z.w = 0.f;
            *(vfloat4*)(t + base) = z;
        }
        return;
    }

    const vfloat4* __restrict__ pr = (const vfloat4*)(proj + (size_t)b * DD);
    vfloat4 p[4];
#pragma unroll
    for (int k = 0; k < 4; ++k)
        p[k] = pr[lane + 64 * k];

    const vfloat4* __restrict__ x0 = (const vfloat4*)(x + base * (size_t)DD);

    float acc[4] = {0.f, 0.f, 0.f, 0.f};
#pragma unroll
    for (int r = 0; r < 4; ++r) {
        if (msk[r]) {                          // wave-uniform branch
#pragma unroll
            for (int k = 0; k < 4; ++k) {
                const vfloat4 xv = x0[r * 256 + lane + 64 * k];  // plain load
                acc[r] += xv.x * p[k].x + xv.y * p[k].y +
                          xv.z * p[k].z + xv.w * p[k].w;
            }
        }
    }
#pragma unroll
    for (int off = 32; off >= 1; off >>= 1) {
#pragma unroll
        for (int r = 0; r < 4; ++r)
            acc[r] += __shfl_xor(acc[r], off, 64);
    }
    if (lane == 0) {
        vfloat4 o;
        o.x = msk[0] ? expf(tanhf(acc[0])) : 0.f;
        o.y = msk[1] ? expf(tanhf(acc[1])) : 0.f;
        o.z = msk[2] ? expf(tanhf(acc[2])) : 0.f;
        o.w = msk[3] ? expf(tanhf(acc[3])) : 0.f;
        *(vfloat4*)(t + base) = o;             // coalesced 16B store
    }
}

// ---------------------------------------------------------------------------
// Kernel 3: in-place normalize: out[b,s] /= (sum_s out[b,s] + EPS)
// ---------------------------------------------------------------------------
__global__ __launch_bounds__(256) void norm_kernel(float* __restrict__ out) {
    const int b = blockIdx.x;
    float* __restrict__ row = out + (size_t)b * SS;

    float vals[8];
    float sum = 0.f;
#pragma unroll
    for (int k = 0; k < 8; ++k) {
        vals[k] = row[threadIdx.x + 256 * k];
        sum += vals[k];
    }
#pragma unroll
    for (int off = 32; off >= 1; off >>= 1)
        sum += __shfl_xor(sum, off, 64);

    __shared__ float wsum[4];
    const int lane = threadIdx.x & 63;
    const int wid  = threadIdx.x >> 6;
    if (lane == 0) wsum[wid] = sum;
    __syncthreads();
    const float total = wsum[0] + wsum[1] + wsum[2] + wsum[3];
    const float inv = 1.0f / (total + EPSF);

#pragma unroll
    for (int k = 0; k < 8; ++k)
        row[threadIdx.x + 256 * k] = vals[k] * inv;
}

extern "C" void kernel_launch(void* const* d_in, const int* in_sizes, int n_in,
                              void* d_out, int out_size, void* d_ws, size_t ws_size,
                              hipStream_t stream) {
    const float* x    = (const float*)d_in[0];   // [B,S,D]
    const float* y    = (const float*)d_in[1];   // [B,D]
    const int*   mask = (const int*)d_in[2];     // [B,S]
    const float* M    = (const float*)d_in[3];   // [D,D]
    float* out  = (float*)d_out;                 // [B,S]
    float* proj = (float*)d_ws;                  // [B,D] = 128 KB scratch

    proj_kernel<<<512, 256, 0, stream>>>(y, M, proj);
    score_kernel<<<(BB * SS / 4) / 4, 256, 0, stream>>>(x, mask, proj, out);
    norm_kernel<<<BB, 256, 0, stream>>>(out);
}